// Round 1
// 1464.609 us; speedup vs baseline: 1.1942x; 1.1942x over previous
//
#include <hip/hip_runtime.h>
#include <hip/hip_bf16.h>

// Problem dims (fixed by the reference)
#define M_TOTAL 8192     // B*T = 4*2048
#define K_DIM   4096     // n (input dim, normalized over)
#define H_DIM   16384    // n_hidden

#define BM 256
#define BN 256
#define BK 64
#define NKT (K_DIM / BK)   // 64 K-tiles

typedef __attribute__((ext_vector_type(8))) short   short8;   // 8 bf16 = 4 VGPRs
typedef __attribute__((ext_vector_type(4))) float   f32x4;
typedef __attribute__((ext_vector_type(8))) unsigned short u16x8;

// RNE float -> bf16
static __device__ __forceinline__ unsigned short f2bf(float f) {
    unsigned int x = __float_as_uint(f);
    x += 0x7fffu + ((x >> 16) & 1u);
    return (unsigned short)(x >> 16);
}

// ---------------------------------------------------------------------------
// Kernel 1: straight cast g (fp32, [M][K]) -> bf16
// ---------------------------------------------------------------------------
__global__ void cast_bf16_kernel(const float* __restrict__ in,
                                 unsigned short* __restrict__ out, long n) {
    long i = ((long)blockIdx.x * blockDim.x + threadIdx.x) * 8;
    if (i >= n) return;
    const float4* p = (const float4*)(in + i);
    float4 a = p[0];
    float4 b = p[1];
    u16x8 o;
    o[0] = f2bf(a.x); o[1] = f2bf(a.y); o[2] = f2bf(a.z); o[3] = f2bf(a.w);
    o[4] = f2bf(b.x); o[5] = f2bf(b.y); o[6] = f2bf(b.z); o[7] = f2bf(b.w);
    *(u16x8*)(out + i) = o;
}

// ---------------------------------------------------------------------------
// Kernel 2: W [K][H] fp32 -> Wt [H][K] bf16  (LDS 64x64 tile transpose)
//           + fused column sum-of-squares into norm2[H]
// ---------------------------------------------------------------------------
__global__ void transpose_norm_kernel(const float* __restrict__ W,
                                      unsigned short* __restrict__ Wt,
                                      float* __restrict__ norm2) {
    __shared__ float tile[64][65];   // +1 pad
    __shared__ float np[64];
    const int h0 = blockIdx.x * 64;
    const int n0 = blockIdx.y * 64;
    const int t  = threadIdx.x;
    const int c  = t & 63;           // fast dim (coalesced global read over h)
    const int r4 = t >> 6;           // 0..3

    if (t < 64) np[t] = 0.f;
    __syncthreads();

    float sq = 0.f;
#pragma unroll
    for (int it = 0; it < 16; ++it) {
        int r = it * 4 + r4;         // n-row within tile
        float v = W[(size_t)(n0 + r) * H_DIM + h0 + c];
        tile[r][c] = v;              // tile[n][h]
        sq += v * v;
    }
    atomicAdd(&np[c], sq);           // LDS atomic, per h-column
    __syncthreads();

    // Write: Wt[h][n], each lane emits 16B (8 bf16 along n)
    const int chunk = t & 7;         // n-chunk (8 elements)
    const int hr    = t >> 3;        // 0..31
#pragma unroll
    for (int it = 0; it < 2; ++it) {
        int hrow = hr + it * 32;
        u16x8 o;
#pragma unroll
        for (int j = 0; j < 8; ++j)
            o[j] = f2bf(tile[chunk * 8 + j][hrow]);
        *(u16x8*)&Wt[(size_t)(h0 + hrow) * K_DIM + n0 + chunk * 8] = o;
    }
    if (t < 64) atomicAdd(&norm2[h0 + t], np[t]);
}

// ---------------------------------------------------------------------------
// Kernel 3: 256x256 tile, 8-wave, 4-phase-per-K-tile pipelined bf16 MFMA GEMM
//           with counted-vmcnt staging (T3+T4), setprio around MFMA (T5),
//           XOR-8 chunk swizzle (T2, conflict-free ds_read_b128), XCD-chunked
//           block swizzle (T1), fused exp / row-sum / atomicAdd epilogue.
//
// Staging schedule (derived from LDS region-death times; issue >= death so
// global_load_lds writes can never land on a region still being read):
//   A(t) LDS rows: quarters q=fm/2: rows {wm*128 + q*32 + [0,32)} -> quarter q
//     dead after phase q+1.  B(t): fully register-held after phase 1.
//   ph1: stage A(t+1) h1 (rows 64..127,192..255 of buf^1; dead since t-1 ph4)
//   ph2: stage B(t+1) h0+h1 (buf^1 B; dead since t-1 ph1)
//   ph3: stage A(t+2) h0 (rows 0..63,128..191 of buf; dead after ph2 of t)
//   boundary: s_waitcnt vmcnt(2) (A(t+2) h0 may stay in flight) + s_barrier
// ---------------------------------------------------------------------------
__global__ __launch_bounds__(512)
void gemm_lse_kernel(const unsigned short* __restrict__ A,
                     const unsigned short* __restrict__ Bt,
                     const float* __restrict__ norm2,
                     float* __restrict__ sums) {
    __shared__ __attribute__((aligned(16))) unsigned short As[2][BM][BK]; // 64 KB
    __shared__ __attribute__((aligned(16))) unsigned short Bs[2][BN][BK]; // 64 KB

    const int tid  = threadIdx.x;
    const int wave = tid >> 6;
    const int lane = tid & 63;
    const int l15  = lane & 15;
    const int quad = lane >> 4;
    const int wm   = wave >> 2;    // 0..1  (m half: 128 rows)
    const int wn   = wave & 3;     // 0..3  (n quarter: 64 cols)

    // ---- block -> (m0,h0): XCD-chunked, 16x16 supertile per XCD ----
    // grid = 2048 = 8 XCDs x 256; XCD x owns mb in [ (x&1)*16, +16 ),
    // hb in [ (x>>1)*16, +16 ).  32 resident blocks/XCD share 16 A-strips +
    // 2 B-strips -> hot K-slice ~576 KB, fits 4 MB XCD L2.
    const int bid = blockIdx.x;
    const int xcd = bid & 7;
    const int li  = bid >> 3;                       // 0..255
    const int m0  = ((xcd & 1) * 16 + (li & 15)) * BM;   // mb 0..31
    const int h0  = ((xcd >> 1) * 16 + (li >> 4)) * BN;  // hb 0..63

    // staging: linear LDS dest (base + lane*16), pre-swizzled global source.
    // lane -> row (lane>>3), LDS slot (lane&7) holds source chunk (lane&7)^row.
    const int ri = lane >> 3;
    const int sc = ((lane & 7) ^ ri) * 8;
    const unsigned short* ag = A  + (size_t)(m0 + wave * 8 + ri) * K_DIM + sc;
    const unsigned short* bg = Bt + (size_t)(h0 + wave * 8 + ri) * K_DIM + sc;

#define STAGE_A(BF_, BASE_, KT_)                                               \
    __builtin_amdgcn_global_load_lds(                                          \
        (const __attribute__((address_space(1))) void*)                        \
            (ag + (size_t)(BASE_) * K_DIM + (KT_) * BK),                       \
        (__attribute__((address_space(3))) void*)&As[BF_][(BASE_) + wave * 8][0], \
        16, 0, 0)
#define STAGE_B(BF_, BASE_, KT_)                                               \
    __builtin_amdgcn_global_load_lds(                                          \
        (const __attribute__((address_space(1))) void*)                        \
            (bg + (size_t)(BASE_) * K_DIM + (KT_) * BK),                       \
        (__attribute__((address_space(3))) void*)&Bs[BF_][(BASE_) + wave * 8][0], \
        16, 0, 0)

    // fragment reads: chunk c = ks*4+quad of row, at swizzled slot c^(row&7)
    const int arow = wm * 128 + l15;
    const int brow = wn * 64 + l15;
    const int sl0  = ((quad)     ^ (l15 & 7)) * 8;
    const int sl1  = ((4 + quad) ^ (l15 & 7)) * 8;

#define LDA(D_, BF_, FM_, KS_) D_ = *(const short8*)&As[BF_][arow + (FM_) * 16][(KS_) ? sl1 : sl0]
#define LDB(D_, BF_, FN_, KS_) D_ = *(const short8*)&Bs[BF_][brow + (FN_) * 16][(KS_) ? sl1 : sl0]
#define MFMA(A_, B_, C_) C_ = __builtin_amdgcn_mfma_f32_16x16x32_bf16(A_, B_, C_, 0, 0, 0)

    f32x4 acc[8][4];
#pragma unroll
    for (int i = 0; i < 8; ++i)
#pragma unroll
        for (int j = 0; j < 4; ++j)
            acc[i][j] = (f32x4){0.f, 0.f, 0.f, 0.f};

    // ---- prologue: tile 0 fully + A1 h0; leave A1 h0 in flight ----
    STAGE_A(0, 0, 0);   STAGE_A(0, 128, 0);    // A0 h0
    STAGE_A(0, 64, 0);  STAGE_A(0, 192, 0);    // A0 h1
    STAGE_B(0, 0, 0);   STAGE_B(0, 64, 0);     // B0 h0
    STAGE_B(0, 128, 0); STAGE_B(0, 192, 0);    // B0 h1
    STAGE_A(1, 0, 1);   STAGE_A(1, 128, 1);    // A1 h0
    asm volatile("s_waitcnt vmcnt(2)" ::: "memory");
    __builtin_amdgcn_s_barrier();

    short8 b[4][2];
    short8 a00, a01, a10, a11;

#define PHASE_MFMA(Q_)                                                         \
    __builtin_amdgcn_s_barrier();                                              \
    __builtin_amdgcn_s_setprio(1);                                             \
    _Pragma("unroll")                                                          \
    for (int fn = 0; fn < 4; ++fn) {                                           \
        MFMA(a00, b[fn][0], acc[2 * (Q_)][fn]);                                \
        MFMA(a01, b[fn][1], acc[2 * (Q_)][fn]);                                \
        MFMA(a10, b[fn][0], acc[2 * (Q_) + 1][fn]);                            \
        MFMA(a11, b[fn][1], acc[2 * (Q_) + 1][fn]);                            \
    }                                                                          \
    __builtin_amdgcn_s_setprio(0)

#pragma unroll 2
    for (int t = 0; t < NKT; ++t) {
        const int buf  = t & 1;
        const int nbuf = buf ^ 1;

        // ---- phase 1: m-frags 0,1 ; read ALL B into regs ; stage A(t+1) h1
        LDA(a00, buf, 0, 0); LDA(a01, buf, 0, 1);
        LDA(a10, buf, 1, 0); LDA(a11, buf, 1, 1);
#pragma unroll
        for (int fn = 0; fn < 4; ++fn) {
            LDB(b[fn][0], buf, fn, 0);
            LDB(b[fn][1], buf, fn, 1);
        }
        if (t < NKT - 1) { STAGE_A(nbuf, 64, t + 1); STAGE_A(nbuf, 192, t + 1); }
        PHASE_MFMA(0);
        __builtin_amdgcn_s_barrier();

        // ---- phase 2: m-frags 2,3 ; stage B(t+1) h0+h1
        LDA(a00, buf, 2, 0); LDA(a01, buf, 2, 1);
        LDA(a10, buf, 3, 0); LDA(a11, buf, 3, 1);
        if (t < NKT - 1) {
            STAGE_B(nbuf, 0, t + 1);   STAGE_B(nbuf, 64, t + 1);
            STAGE_B(nbuf, 128, t + 1); STAGE_B(nbuf, 192, t + 1);
        }
        PHASE_MFMA(1);
        __builtin_amdgcn_s_barrier();

        // ---- phase 3: m-frags 4,5 ; stage A(t+2) h0 (same parity buffer)
        LDA(a00, buf, 4, 0); LDA(a01, buf, 4, 1);
        LDA(a10, buf, 5, 0); LDA(a11, buf, 5, 1);
        if (t < NKT - 2) { STAGE_A(buf, 0, t + 2); STAGE_A(buf, 128, t + 2); }
        PHASE_MFMA(2);
        __builtin_amdgcn_s_barrier();

        // ---- phase 4: m-frags 6,7
        LDA(a00, buf, 6, 0); LDA(a01, buf, 6, 1);
        LDA(a10, buf, 7, 0); LDA(a11, buf, 7, 1);
        PHASE_MFMA(3);

        // ---- K-tile boundary: counted vmcnt (never 0 until the tail)
        if (t < NKT - 2) {
            asm volatile("s_waitcnt vmcnt(2)" ::: "memory");
            __builtin_amdgcn_s_barrier();
        } else if (t == NKT - 2) {
            asm volatile("s_waitcnt vmcnt(0)" ::: "memory");
            __builtin_amdgcn_s_barrier();
        }
    }

    // ---- epilogue. C/D layout: row = quad*4 + reg, col = lane&15 ----
    float rn[4];
#pragma unroll
    for (int fn = 0; fn < 4; ++fn)
        rn[fn] = rsqrtf(norm2[h0 + wn * 64 + fn * 16 + l15]);

#pragma unroll
    for (int fm = 0; fm < 8; ++fm) {
#pragma unroll
        for (int r2 = 0; r2 < 4; ++r2) {
            float s = 0.f;
#pragma unroll
            for (int fn = 0; fn < 4; ++fn)
                s += __expf(acc[fm][fn][r2] * rn[fn]);
            s += __shfl_xor(s, 1);
            s += __shfl_xor(s, 2);
            s += __shfl_xor(s, 4);
            s += __shfl_xor(s, 8);
            if (l15 == 0)
                atomicAdd(&sums[m0 + wm * 128 + fm * 16 + quad * 4 + r2], s);
        }
    }
#undef STAGE_A
#undef STAGE_B
#undef LDA
#undef LDB
#undef MFMA
#undef PHASE_MFMA
}

// ---------------------------------------------------------------------------
// Kernel 4: out[m] = log(sums[m])   (BETA = 1)
// ---------------------------------------------------------------------------
__global__ void finalize_kernel(const float* __restrict__ sums,
                                float* __restrict__ out, int n) {
    int i = blockIdx.x * blockDim.x + threadIdx.x;
    if (i < n) out[i] = logf(sums[i]);
}

// ---------------------------------------------------------------------------
extern "C" void kernel_launch(void* const* d_in, const int* in_sizes, int n_in,
                              void* d_out, int out_size, void* d_ws, size_t ws_size,
                              hipStream_t stream) {
    const float* g = (const float*)d_in[0];   // [4,2048,4096] fp32
    const float* W = (const float*)d_in[1];   // [4096,16384] fp32
    float* out = (float*)d_out;               // [8192] fp32

    char* ws = (char*)d_ws;
    unsigned short* gbf   = (unsigned short*)ws;                              // 64 MB
    unsigned short* wt    = (unsigned short*)(ws + (size_t)67108864);         // 128 MB
    float*          norm2 = (float*)(ws + (size_t)67108864 + 134217728);      // 64 KB
    float*          sums  = (float*)(ws + (size_t)67108864 + 134217728 + 65536); // 32 KB

    hipMemsetAsync(norm2, 0, (H_DIM + M_TOTAL) * sizeof(float), stream);

    cast_bf16_kernel<<<(M_TOTAL * (long)K_DIM) / (256 * 8), 256, 0, stream>>>(
        g, gbf, (long)M_TOTAL * K_DIM);

    transpose_norm_kernel<<<dim3(H_DIM / 64, K_DIM / 64), 256, 0, stream>>>(
        W, wt, norm2);

    gemm_lse_kernel<<<(H_DIM / BN) * (M_TOTAL / BM), 512, 0, stream>>>(
        gbf, wt, norm2, sums);

    finalize_kernel<<<(M_TOTAL + 255) / 256, 256, 0, stream>>>(sums, out, M_TOTAL);
}

// Round 2
// 1352.256 us; speedup vs baseline: 1.2934x; 1.0831x over previous
//
#include <hip/hip_runtime.h>
#include <hip/hip_bf16.h>

// Problem dims (fixed by the reference)
#define M_TOTAL 8192     // B*T = 4*2048
#define K_DIM   4096     // n (input dim, normalized over)
#define H_DIM   16384    // n_hidden

#define BM 256
#define BN 256
#define BK 64
#define NKT (K_DIM / BK)   // 64 K-tiles

typedef __attribute__((ext_vector_type(8))) short   short8;   // 8 bf16 = 4 VGPRs
typedef __attribute__((ext_vector_type(4))) float   f32x4;
typedef __attribute__((ext_vector_type(8))) unsigned short u16x8;

// RNE float -> bf16
static __device__ __forceinline__ unsigned short f2bf(float f) {
    unsigned int x = __float_as_uint(f);
    x += 0x7fffu + ((x >> 16) & 1u);
    return (unsigned short)(x >> 16);
}

// ---------------------------------------------------------------------------
// Kernel 1: straight cast g (fp32, [M][K]) -> bf16
// ---------------------------------------------------------------------------
__global__ void cast_bf16_kernel(const float* __restrict__ in,
                                 unsigned short* __restrict__ out, long n) {
    long i = ((long)blockIdx.x * blockDim.x + threadIdx.x) * 8;
    if (i >= n) return;
    const float4* p = (const float4*)(in + i);
    float4 a = p[0];
    float4 b = p[1];
    u16x8 o;
    o[0] = f2bf(a.x); o[1] = f2bf(a.y); o[2] = f2bf(a.z); o[3] = f2bf(a.w);
    o[4] = f2bf(b.x); o[5] = f2bf(b.y); o[6] = f2bf(b.z); o[7] = f2bf(b.w);
    *(u16x8*)(out + i) = o;
}

// ---------------------------------------------------------------------------
// Kernel 2: W [K][H] fp32 -> Wt [H][K] bf16  (LDS 64x64 tile transpose)
//           + fused column sum-of-squares into norm2[H]
// ---------------------------------------------------------------------------
__global__ void transpose_norm_kernel(const float* __restrict__ W,
                                      unsigned short* __restrict__ Wt,
                                      float* __restrict__ norm2) {
    __shared__ float tile[64][65];   // +1 pad
    __shared__ float np[64];
    const int h0 = blockIdx.x * 64;
    const int n0 = blockIdx.y * 64;
    const int t  = threadIdx.x;
    const int c  = t & 63;           // fast dim (coalesced global read over h)
    const int r4 = t >> 6;           // 0..3

    if (t < 64) np[t] = 0.f;
    __syncthreads();

    float sq = 0.f;
#pragma unroll
    for (int it = 0; it < 16; ++it) {
        int r = it * 4 + r4;         // n-row within tile
        float v = W[(size_t)(n0 + r) * H_DIM + h0 + c];
        tile[r][c] = v;              // tile[n][h]
        sq += v * v;
    }
    atomicAdd(&np[c], sq);           // LDS atomic, per h-column
    __syncthreads();

    // Write: Wt[h][n], each lane emits 16B (8 bf16 along n)
    const int chunk = t & 7;         // n-chunk (8 elements)
    const int hr    = t >> 3;        // 0..31
#pragma unroll
    for (int it = 0; it < 2; ++it) {
        int hrow = hr + it * 32;
        u16x8 o;
#pragma unroll
        for (int j = 0; j < 8; ++j)
            o[j] = f2bf(tile[chunk * 8 + j][hrow]);
        *(u16x8*)&Wt[(size_t)(h0 + hrow) * K_DIM + n0 + chunk * 8] = o;
    }
    if (t < 64) atomicAdd(&norm2[h0 + t], np[t]);
}

// ---------------------------------------------------------------------------
// Kernel 3: 256x256 / BK=64 / 8-wave bf16 MFMA GEMM, ks-split 4-phase schedule
//           with ONE-PHASE-AHEAD REGISTER PREFETCH of all fragments.
//
// Phases (tile t): ph1 = ks0/fm0-3, ph2 = ks1/fm0-3, ph3 = ks0/fm4-7,
//                  ph4 = ks1/fm4-7.  Fragment sets S0/S1 ping-pong:
//   S0 = {sa0[4], sb0[4]}  used ph1 (lo,ks0) and ph3 (hi,ks0; B persists)
//   S1 = {sa1[4], sb1[4]}  used ph2 (lo,ks1) and ph4 (hi,ks1; B persists)
// Every phase's ds_reads were issued one phase earlier -> they overlap the
// previous MFMA cluster; boundary serial window = 0 reads (B staged 2 tiles
// ahead so B(t+1)/A(t+1)lo are prefetched during ph4 of tile t).
//
// Staging per tile: ph1: A(t+1)h1 (2), ph3: A(t+2)h0 (2), ph4: B(t+2) (4).
// Counted-wait ledger (steady state, oldest->newest at each wait point):
//   ph1 vmcnt(8): [Ah1(t) | Ah0(t+1) B(t+1) Ah1(t+1)] -> completes Ah1(t)
//                 (needed by ph2's hi-ks0 reads)
//   ph3 vmcnt(4): [Ah0(t+1) B(t+1) | Ah1(t+1) Ah0(t+2)] -> completes
//                 Ah0(t+1)+B(t+1) (needed by ph4's next-tile prefetch)
// WAR safety (stage vs prior register reads): every overwritten LDS region's
// last ds_read is lgkm-drained before its consuming MFMA, which precedes a
// barrier that precedes the stage issue.  (checked per region)
// ---------------------------------------------------------------------------
__global__ __launch_bounds__(512, 2)
void gemm_lse_kernel(const unsigned short* __restrict__ A,
                     const unsigned short* __restrict__ Bt,
                     const float* __restrict__ norm2,
                     float* __restrict__ sums) {
    __shared__ __attribute__((aligned(16))) unsigned short As[2][BM][BK]; // 64 KB
    __shared__ __attribute__((aligned(16))) unsigned short Bs[2][BN][BK]; // 64 KB

    const int tid  = threadIdx.x;
    const int wave = tid >> 6;
    const int lane = tid & 63;
    const int l15  = lane & 15;
    const int quad = lane >> 4;
    const int wm   = wave >> 2;    // 0..1  (m half: 128 rows)
    const int wn   = wave & 3;     // 0..3  (n quarter: 64 cols)

    // ---- block -> (m0,h0): XCD-chunked, 16x16 supertile per XCD ----
    const int bid = blockIdx.x;
    const int xcd = bid & 7;
    const int li  = bid >> 3;                       // 0..255
    const int m0  = ((xcd & 1) * 16 + (li & 15)) * BM;   // mb 0..31
    const int h0  = ((xcd >> 1) * 16 + (li >> 4)) * BN;  // hb 0..63

    // staging: linear LDS dest (base + lane*16), pre-swizzled global source.
    const int ri = lane >> 3;
    const int sc = ((lane & 7) ^ ri) * 8;
    const unsigned short* ag = A  + (size_t)(m0 + wave * 8 + ri) * K_DIM + sc;
    const unsigned short* bg = Bt + (size_t)(h0 + wave * 8 + ri) * K_DIM + sc;

#define STAGE_A(BF_, BASE_, KT_)                                               \
    __builtin_amdgcn_global_load_lds(                                          \
        (const __attribute__((address_space(1))) void*)                        \
            (ag + (size_t)(BASE_) * K_DIM + (KT_) * BK),                       \
        (__attribute__((address_space(3))) void*)&As[BF_][(BASE_) + wave * 8][0], \
        16, 0, 0)
#define STAGE_B(BF_, BASE_, KT_)                                               \
    __builtin_amdgcn_global_load_lds(                                          \
        (const __attribute__((address_space(1))) void*)                        \
            (bg + (size_t)(BASE_) * K_DIM + (KT_) * BK),                       \
        (__attribute__((address_space(3))) void*)&Bs[BF_][(BASE_) + wave * 8][0], \
        16, 0, 0)

    // fragment reads: chunk c = ks*4+quad of row, at swizzled slot c^(row&7)
    const int arow = wm * 128 + l15;
    const int brow = wn * 64 + l15;
    const int sl0  = ((quad)     ^ (l15 & 7)) * 8;
    const int sl1  = ((4 + quad) ^ (l15 & 7)) * 8;

#define LDA(D_, BF_, FM_, KS_) D_ = *(const short8*)&As[BF_][arow + (FM_) * 16][(KS_) ? sl1 : sl0]
#define LDB(D_, BF_, FN_, KS_) D_ = *(const short8*)&Bs[BF_][brow + (FN_) * 16][(KS_) ? sl1 : sl0]

    f32x4 acc[8][4];
#pragma unroll
    for (int i = 0; i < 8; ++i)
#pragma unroll
        for (int j = 0; j < 4; ++j)
            acc[i][j] = (f32x4){0.f, 0.f, 0.f, 0.f};

    short8 sa0[4], sb0[4], sa1[4], sb1[4];

#define CLUSTER(FB_, SA_, SB_)                                                 \
    __builtin_amdgcn_s_barrier();                                              \
    __builtin_amdgcn_s_setprio(1);                                             \
    _Pragma("unroll")                                                          \
    for (int fm = 0; fm < 4; ++fm)                                             \
        _Pragma("unroll")                                                      \
        for (int fn = 0; fn < 4; ++fn)                                         \
            acc[(FB_) + fm][fn] = __builtin_amdgcn_mfma_f32_16x16x32_bf16(     \
                SA_[fm], SB_[fn], acc[(FB_) + fm][fn], 0, 0, 0);               \
    __builtin_amdgcn_s_setprio(0);                                             \
    __builtin_amdgcn_s_barrier()

    // ---- prologue: A(0) full, B(0), A(1)h0, B(1); leave last 6 in flight --
    STAGE_A(0, 0, 0);   STAGE_A(0, 128, 0);    // A0 h0
    STAGE_A(0, 64, 0);  STAGE_A(0, 192, 0);    // A0 h1
    STAGE_B(0, 0, 0);   STAGE_B(0, 64, 0);     // B0
    STAGE_B(0, 128, 0); STAGE_B(0, 192, 0);
    STAGE_A(1, 0, 1);   STAGE_A(1, 128, 1);    // A1 h0
    STAGE_B(1, 0, 1);   STAGE_B(1, 64, 1);     // B1
    STAGE_B(1, 128, 1); STAGE_B(1, 192, 1);
    asm volatile("s_waitcnt vmcnt(6)" ::: "memory");
    __builtin_amdgcn_s_barrier();

    // pre-loop prefetch: S0 <- {A(0) lo ks0, B(0) ks0}
    LDA(sa0[0], 0, 0, 0); LDA(sa0[1], 0, 1, 0);
    LDA(sa0[2], 0, 2, 0); LDA(sa0[3], 0, 3, 0);
    LDB(sb0[0], 0, 0, 0); LDB(sb0[1], 0, 1, 0);
    LDB(sb0[2], 0, 2, 0); LDB(sb0[3], 0, 3, 0);

#pragma unroll 2
    for (int t = 0; t < NKT; ++t) {
        const int buf  = t & 1;
        const int nbuf = buf ^ 1;

        // ---- ph1 (MFMA: lo, ks0 on S0) ------------------------------------
        LDA(sa1[0], buf, 0, 1); LDA(sa1[1], buf, 1, 1);   // S1 <- A lo ks1
        LDA(sa1[2], buf, 2, 1); LDA(sa1[3], buf, 3, 1);
        LDB(sb1[0], buf, 0, 1); LDB(sb1[1], buf, 1, 1);   // S1 <- B ks1
        LDB(sb1[2], buf, 2, 1); LDB(sb1[3], buf, 3, 1);
        if (t < NKT - 1) { STAGE_A(nbuf, 64, t + 1); STAGE_A(nbuf, 192, t + 1); }
        asm volatile("s_waitcnt vmcnt(8)" ::: "memory");   // completes Ah1(t)
        CLUSTER(0, sa0, sb0);

        // ---- ph2 (MFMA: lo, ks1 on S1) ------------------------------------
        LDA(sa0[0], buf, 4, 0); LDA(sa0[1], buf, 5, 0);   // S0.A <- A hi ks0
        LDA(sa0[2], buf, 6, 0); LDA(sa0[3], buf, 7, 0);
        CLUSTER(0, sa1, sb1);

        // ---- ph3 (MFMA: hi, ks0 on S0) ------------------------------------
        LDA(sa1[0], buf, 4, 1); LDA(sa1[1], buf, 5, 1);   // S1.A <- A hi ks1
        LDA(sa1[2], buf, 6, 1); LDA(sa1[3], buf, 7, 1);
        if (t < NKT - 2) { STAGE_A(buf, 0, t + 2); STAGE_A(buf, 128, t + 2); }
        asm volatile("s_waitcnt vmcnt(4)" ::: "memory");   // Ah0(t+1)+B(t+1)
        CLUSTER(4, sa0, sb0);

        // ---- ph4 (MFMA: hi, ks1 on S1) ------------------------------------
        if (t < NKT - 1) {
            LDA(sa0[0], nbuf, 0, 0); LDA(sa0[1], nbuf, 1, 0); // S0 <- A(t+1) lo ks0
            LDA(sa0[2], nbuf, 2, 0); LDA(sa0[3], nbuf, 3, 0);
            LDB(sb0[0], nbuf, 0, 0); LDB(sb0[1], nbuf, 1, 0); // S0 <- B(t+1) ks0
            LDB(sb0[2], nbuf, 2, 0); LDB(sb0[3], nbuf, 3, 0);
        }
        if (t < NKT - 2) {
            STAGE_B(buf, 0, t + 2);   STAGE_B(buf, 64, t + 2);   // B(t+2)
            STAGE_B(buf, 128, t + 2); STAGE_B(buf, 192, t + 2);
        }
        CLUSTER(4, sa1, sb1);
    }

    // ---- epilogue. C/D layout: row = quad*4 + reg, col = lane&15 ----
    float rn[4];
#pragma unroll
    for (int fn = 0; fn < 4; ++fn)
        rn[fn] = rsqrtf(norm2[h0 + wn * 64 + fn * 16 + l15]);

#pragma unroll
    for (int fm = 0; fm < 8; ++fm) {
#pragma unroll
        for (int r2 = 0; r2 < 4; ++r2) {
            float s = 0.f;
#pragma unroll
            for (int fn = 0; fn < 4; ++fn)
                s += __expf(acc[fm][fn][r2] * rn[fn]);
            s += __shfl_xor(s, 1);
            s += __shfl_xor(s, 2);
            s += __shfl_xor(s, 4);
            s += __shfl_xor(s, 8);
            if (l15 == 0)
                atomicAdd(&sums[m0 + wm * 128 + fm * 16 + quad * 4 + r2], s);
        }
    }
#undef STAGE_A
#undef STAGE_B
#undef LDA
#undef LDB
#undef CLUSTER
}

// ---------------------------------------------------------------------------
// Kernel 4: out[m] = log(sums[m])   (BETA = 1)
// ---------------------------------------------------------------------------
__global__ void finalize_kernel(const float* __restrict__ sums,
                                float* __restrict__ out, int n) {
    int i = blockIdx.x * blockDim.x + threadIdx.x;
    if (i < n) out[i] = logf(sums[i]);
}

// ---------------------------------------------------------------------------
extern "C" void kernel_launch(void* const* d_in, const int* in_sizes, int n_in,
                              void* d_out, int out_size, void* d_ws, size_t ws_size,
                              hipStream_t stream) {
    const float* g = (const float*)d_in[0];   // [4,2048,4096] fp32
    const float* W = (const float*)d_in[1];   // [4096,16384] fp32
    float* out = (float*)d_out;               // [8192] fp32

    char* ws = (char*)d_ws;
    unsigned short* gbf   = (unsigned short*)ws;                              // 64 MB
    unsigned short* wt    = (unsigned short*)(ws + (size_t)67108864);         // 128 MB
    float*          norm2 = (float*)(ws + (size_t)67108864 + 134217728);      // 64 KB
    float*          sums  = (float*)(ws + (size_t)67108864 + 134217728 + 65536); // 32 KB

    hipMemsetAsync(norm2, 0, (H_DIM + M_TOTAL) * sizeof(float), stream);

    cast_bf16_kernel<<<(M_TOTAL * (long)K_DIM) / (256 * 8), 256, 0, stream>>>(
        g, gbf, (long)M_TOTAL * K_DIM);

    transpose_norm_kernel<<<dim3(H_DIM / 64, K_DIM / 64), 256, 0, stream>>>(
        W, wt, norm2);

    gemm_lse_kernel<<<(H_DIM / BN) * (M_TOTAL / BM), 512, 0, stream>>>(
        gbf, wt, norm2, sums);

    finalize_kernel<<<(M_TOTAL + 255) / 256, 256, 0, stream>>>(sums, out, M_TOTAL);
}